// Round 3
// baseline (163.347 us; speedup 1.0000x reference)
//
#include <hip/hip_runtime.h>
#include <hip/hip_bf16.h>
#include <stdint.h>

// Problem constants
#define NB 2
#define NS 2048
#define NE 1024
#define NH 16
#define ND 64

typedef __attribute__((ext_vector_type(4))) float f32x4;
typedef __attribute__((ext_vector_type(16))) float f32x16;
typedef __attribute__((ext_vector_type(8))) short s16x8;
typedef __attribute__((ext_vector_type(4))) unsigned short u16x4;
typedef __attribute__((ext_vector_type(2))) unsigned int uint2v;

__device__ __forceinline__ unsigned short f2bf(float f) {
  union { float f; unsigned int i; } u; u.f = f;
  unsigned int r = u.i + 0x7FFFu + ((u.i >> 16) & 1u);  // RNE
  return (unsigned short)(r >> 16);
}

__device__ __forceinline__ unsigned cvtpk_bf16(float lo, float hi) {
  unsigned r;
  asm("v_cvt_pk_bf16_f32 %0, %1, %2" : "=v"(r) : "v"(lo), "v"(hi));
  return r;
}

__device__ __forceinline__ void gload_lds16(const void* g, void* l) {
  __builtin_amdgcn_global_load_lds(
      (const __attribute__((address_space(1))) uint32_t*)g,
      (__attribute__((address_space(3))) uint32_t*)l, 16, 0, 0);
}

__device__ __forceinline__ f32x4 mfma16(s16x8 a, s16x8 b, f32x4 c) {
  return __builtin_amdgcn_mfma_f32_16x16x32_bf16(a, b, c, 0, 0, 0);
}
__device__ __forceinline__ f32x16 mfma32(s16x8 a, s16x8 b, f32x16 c) {
  return __builtin_amdgcn_mfma_f32_32x32x16_bf16(a, b, c, 0, 0, 0);
}

// ---------------- f32 -> bf16 converts (fused) ----------------
__global__ void conv_x2(const float* __restrict__ a, const float* __restrict__ b,
                        unsigned short* __restrict__ da, unsigned short* __restrict__ db,
                        int n4) {
  const float* s = blockIdx.y ? b : a;
  unsigned short* d = blockIdx.y ? db : da;
  int i = blockIdx.x * blockDim.x + threadIdx.x;
  int stride = gridDim.x * blockDim.x;
  for (; i < n4; i += stride) {
    float4 v = ((const float4*)s)[i];
    u16x4 o;
    o.x = f2bf(v.x); o.y = f2bf(v.y); o.z = f2bf(v.z); o.w = f2bf(v.w);
    ((u16x4*)d)[i] = o;
  }
}

__global__ void conv_w4(const float* __restrict__ s0, const float* __restrict__ s1,
                        const float* __restrict__ s2, const float* __restrict__ s3,
                        unsigned short* __restrict__ d0, unsigned short* __restrict__ d1,
                        unsigned short* __restrict__ d2, unsigned short* __restrict__ d3,
                        int n4) {
  const float* s; unsigned short* d;
  switch (blockIdx.y) {
    case 0: s = s0; d = d0; break;
    case 1: s = s1; d = d1; break;
    case 2: s = s2; d = d2; break;
    default: s = s3; d = d3; break;
  }
  int i = blockIdx.x * blockDim.x + threadIdx.x;
  int stride = gridDim.x * blockDim.x;
  for (; i < n4; i += stride) {
    float4 v = ((const float4*)s)[i];
    u16x4 o;
    o.x = f2bf(v.x); o.y = f2bf(v.y); o.z = f2bf(v.z); o.w = f2bf(v.w);
    ((u16x4*)d)[i] = o;
  }
}

// ---------------- GEMM: C = A[M,K] * W[N,K]^T + bias (M=4096, K=1024) ----------------
// Double-buffered LDS, counted vmcnt, raw barriers (T3+T4-lite).
// EPI 0: bf16 out row-major [M,1024] (out0, W0, b0)
// EPI 2: f32  out row-major [M,1024]
// EPI 3: merged KV, N=2048: cols <1024 -> out0 bf16 row-major (W0,b0);
//        cols >=1024 -> out1 bf16 head-transposed [(b*NE+nv)*NS+s] (W1,b1)
template <int EPI>
__global__ __launch_bounds__(256, 2) void gemm_bt(
    const unsigned short* __restrict__ A,
    const unsigned short* __restrict__ W0, const unsigned short* __restrict__ W1,
    const float* __restrict__ b0, const float* __restrict__ b1,
    void* __restrict__ out0, void* __restrict__ out1) {
  constexpr int BM = 64;             // block rows; 2x2 waves of 32x64
  constexpr int K = 1024;
  __shared__ char smem[2 * (BM * 128 + 16384)];
  const int t = threadIdx.x;
  const int lane = t & 63;
  const int wv = t >> 6;
  const int wr = wv >> 1, wc = wv & 1;
  const int bm = blockIdx.y * BM, bn = blockIdx.x * 128;
  const int lr = lane & 15, lg = lane >> 4;

  const unsigned short* Wp = W0;
  const float* bp = b0;
  int nloc = bn;
  if constexpr (EPI == 3) {
    if (bn >= 1024) { Wp = W1; bp = b1; nloc = bn - 1024; }
  }

  f32x4 acc[2][4] = {};

  auto stage = [&](int buf, int k0) {
    char* As = smem + buf * (BM * 128 + 16384);
    char* Bs = As + BM * 128;
#pragma unroll
    for (int r = 0; r < BM / 32; ++r) {
      int lin = r * 256 + t;
      int row = lin >> 3;
      int scb = ((lin & 7) << 4) ^ ((row & 7) << 4);
      gload_lds16((const char*)(A + (size_t)(bm + row) * K + k0) + scb,
                  As + (size_t)(r * 256 + (t & ~63)) * 16);
    }
#pragma unroll
    for (int r = 0; r < 4; ++r) {
      int lin = r * 256 + t;
      int row = lin >> 3;
      int scb = ((lin & 7) << 4) ^ ((row & 7) << 4);
      gload_lds16((const char*)(Wp + (size_t)(nloc + row) * K + k0) + scb,
                  Bs + (size_t)(r * 256 + (t & ~63)) * 16);
    }
  };

  stage(0, 0);
  for (int t6 = 0; t6 < K / 64; ++t6) {
    const int cur = t6 & 1;
    if (t6 + 1 < K / 64) {
      stage(cur ^ 1, (t6 + 1) * 64);
      asm volatile("s_waitcnt vmcnt(6)" ::: "memory");  // 6 = next-tile loads in flight
    } else {
      asm volatile("s_waitcnt vmcnt(0)" ::: "memory");
    }
    asm volatile("s_barrier" ::: "memory");

    const char* As = smem + cur * (BM * 128 + 16384);
    const char* Bs = As + BM * 128;
    s16x8 af[2][2], bfr[4][2];
#pragma unroll
    for (int mf = 0; mf < 2; ++mf)
#pragma unroll
      for (int kk = 0; kk < 2; ++kk) {
        int row = wr * 32 + mf * 16 + lr;
        int cb = (lg << 4) + (kk << 6);
        af[mf][kk] = *(const s16x8*)(As + row * 128 + (cb ^ ((row & 7) << 4)));
      }
#pragma unroll
    for (int nf = 0; nf < 4; ++nf)
#pragma unroll
      for (int kk = 0; kk < 2; ++kk) {
        int row = wc * 64 + nf * 16 + lr;
        int cb = (lg << 4) + (kk << 6);
        bfr[nf][kk] = *(const s16x8*)(Bs + row * 128 + (cb ^ ((row & 7) << 4)));
      }
#pragma unroll
    for (int mf = 0; mf < 2; ++mf)
#pragma unroll
      for (int nf = 0; nf < 4; ++nf)
#pragma unroll
        for (int kk = 0; kk < 2; ++kk)
          acc[mf][nf] = mfma16(af[mf][kk], bfr[nf][kk], acc[mf][nf]);

    asm volatile("s_waitcnt lgkmcnt(0)" ::: "memory");  // reads landed before others overwrite
    asm volatile("s_barrier" ::: "memory");
  }

  // epilogue: C/D layout col = lane&15, row = (lane>>4)*4 + reg
#pragma unroll
  for (int mf = 0; mf < 2; ++mf)
#pragma unroll
    for (int nf = 0; nf < 4; ++nf) {
      int m0 = bm + wr * 32 + mf * 16 + (lg << 2);
      int nc = wc * 64 + nf * 16 + lr;
      int n = bn + nc;
      float bv = bp[nloc + nc];
      if constexpr (EPI == 0) {
        unsigned short* C = (unsigned short*)out0;
#pragma unroll
        for (int r = 0; r < 4; ++r)
          C[(size_t)(m0 + r) * 1024 + n] = f2bf(acc[mf][nf][r] + bv);
      } else if constexpr (EPI == 2) {
        float* C = (float*)out0;
#pragma unroll
        for (int r = 0; r < 4; ++r)
          C[(size_t)(m0 + r) * 1024 + n] = acc[mf][nf][r] + bv;
      } else {  // EPI == 3
        if (n < 1024) {
          unsigned short* C = (unsigned short*)out0;
#pragma unroll
          for (int r = 0; r < 4; ++r)
            C[(size_t)(m0 + r) * 1024 + n] = f2bf(acc[mf][nf][r] + bv);
        } else {
          unsigned short* C = (unsigned short*)out1;
          int nv = n - 1024;
          int b = m0 >> 11, s = m0 & 2047;
          u16x4 o;
          o.x = f2bf(acc[mf][nf][0] + bv);
          o.y = f2bf(acc[mf][nf][1] + bv);
          o.z = f2bf(acc[mf][nf][2] + bv);
          o.w = f2bf(acc[mf][nf][3] + bv);
          *(u16x4*)&C[((size_t)b * NE + nv) * NS + s] = o;
        }
      }
    }
}

// ---------------- Flash attention (swapped-operand 32x32, 2-wave blocks) ----------------
// grid (S/64, B*H), 128 threads = 2 waves; each wave owns 32 q-rows.
__global__ __launch_bounds__(128, 3) void attn_fwd(
    const unsigned short* __restrict__ qb, const unsigned short* __restrict__ kb,
    const unsigned short* __restrict__ vt, const int* __restrict__ mask,
    unsigned short* __restrict__ ob) {
  __shared__ char smem[32768];  // 2 x (K 8KB + V 8KB)
  const int t = threadIdx.x, lane = t & 63, wv = t >> 6;
  const int l31 = lane & 31, hi = lane >> 5;
  const int bh = blockIdx.y, b = bh >> 4, h = bh & 15;
  const int q = blockIdx.x * 64 + wv * 32 + l31;
  const float C = 0.18033688f;  // (1/sqrt(64)) * log2(e)

  // Q fragments (B-operand: col=q=lane&31, k = 16*ks + 8*hi + e)
  s16x8 qf[4];
#pragma unroll
  for (int ks = 0; ks < 4; ++ks)
    qf[ks] = *(const s16x8*)&qb[((size_t)(b * NS + q)) * NE + h * ND + ks * 16 + hi * 8];

  f32x16 oacc[2] = {};
  float m = -1e30f, l = 0.f;

  auto stage = [&](int buf, int kt) {
    char* Ks = smem + buf * 16384;
    char* Vs = Ks + 8192;
#pragma unroll
    for (int r = 0; r < 4; ++r) {
      int lin = r * 128 + t;
      int row = lin >> 3;
      int scb = ((lin & 7) << 4) ^ ((row & 7) << 4);
      gload_lds16((const char*)&kb[((size_t)(b * NS + kt + row)) * NE + h * ND] + scb,
                  Ks + (r * 128 + (t & ~63)) * 16);
    }
#pragma unroll
    for (int r = 0; r < 4; ++r) {
      int lin = r * 128 + t;
      int row = lin >> 3;
      int scb = ((lin & 7) << 4) ^ ((row & 7) << 4);
      gload_lds16((const char*)&vt[((size_t)((b * NH + h) * ND + row)) * NS + kt] + scb,
                  Vs + (r * 128 + (t & ~63)) * 16);
    }
  };

  stage(0, 0);
  asm volatile("s_waitcnt vmcnt(0)" ::: "memory");
  __syncthreads();

  for (int kt = 0; kt < NS; kt += 64) {
    const int cur = (kt >> 6) & 1;
    if (kt + 64 < NS) stage(cur ^ 1, kt + 64);
    const char* Ks = smem + cur * 16384;
    const char* Vs = Ks + 8192;

    int mk = mask[b * NS + kt + lane];

    // QK^T (swapped): ST[key][q]
    f32x16 st[2] = {};
    __builtin_amdgcn_s_setprio(1);
#pragma unroll
    for (int t2 = 0; t2 < 2; ++t2)
#pragma unroll
      for (int ks = 0; ks < 4; ++ks) {
        int row = t2 * 32 + l31;
        s16x8 kf = *(const s16x8*)(Ks + row * 128 + ((ks * 32 + hi * 16) ^ ((row & 7) << 4)));
        st[t2] = mfma32(kf, qf[ks], st[t2]);
      }
    __builtin_amdgcn_s_setprio(0);

    // tile max: pairwise then max3-shaped tree, one cross-half exchange
    float tm[16];
#pragma unroll
    for (int r = 0; r < 16; ++r) tm[r] = fmaxf(st[0][r], st[1][r]);
    float a0 = fmaxf(fmaxf(tm[0], tm[1]), tm[2]);
    float a1 = fmaxf(fmaxf(tm[3], tm[4]), tm[5]);
    float a2 = fmaxf(fmaxf(tm[6], tm[7]), tm[8]);
    float a3 = fmaxf(fmaxf(tm[9], tm[10]), tm[11]);
    float a4 = fmaxf(fmaxf(tm[12], tm[13]), tm[14]);
    float b0 = fmaxf(fmaxf(a0, a1), a2);
    float b1 = fmaxf(fmaxf(a3, a4), tm[15]);
    float mxl = fmaxf(b0, b1);
    float mx = fmaxf(mxl, __shfl_xor(mxl, 32));

    // defer-max (T13)
    if (!__all(mx - m <= 44.0f)) {
      float mnew = fmaxf(m, mx);
      float corr = __builtin_amdgcn_exp2f((m - mnew) * C);
#pragma unroll
      for (int td = 0; td < 2; ++td)
#pragma unroll
        for (int r = 0; r < 16; ++r) oacc[td][r] *= corr;
      l *= corr;
      m = mnew;
    }
    const float mC = m * C;

    // exp in place
#pragma unroll
    for (int t2 = 0; t2 < 2; ++t2)
#pragma unroll
      for (int r = 0; r < 16; ++r)
        st[t2][r] = __builtin_amdgcn_exp2f(__builtin_fmaf(st[t2][r], C, -mC));

    // mask: zero p of masked keys (softmax invariant to inflated m)
    unsigned long long bal = __ballot(mk != 0);
    if (bal != ~0ull) {
#pragma unroll
      for (int t2 = 0; t2 < 2; ++t2)
#pragma unroll
        for (int r = 0; r < 16; ++r) {
          int key = t2 * 32 + (r & 3) + 8 * (r >> 2) + 4 * hi;
          if (!((bal >> key) & 1)) st[t2][r] = 0.f;
        }
    }

    // row sum
    float ps[16];
#pragma unroll
    for (int r = 0; r < 16; ++r) ps[r] = st[0][r] + st[1][r];
#pragma unroll
    for (int s = 8; s > 0; s >>= 1)
#pragma unroll
      for (int r = 0; r < s; ++r) ps[r] += ps[r + s];
    l += ps[0] + __shfl_xor(ps[0], 32);

    // pack P -> PV B-fragments (T12: cvt_pk + permlane32_swap)
    s16x8 pf[4];
#pragma unroll
    for (int ks = 0; ks < 4; ++ks) {
      const int t2 = ks >> 1, r0 = (ks & 1) * 8;
      unsigned wreg[4];
#pragma unroll
      for (int w = 0; w < 2; ++w) {
        unsigned x = cvtpk_bf16(st[t2][r0 + 2 * w], st[t2][r0 + 2 * w + 1]);
        unsigned y = cvtpk_bf16(st[t2][r0 + 4 + 2 * w], st[t2][r0 + 4 + 2 * w + 1]);
        uint2v r2 = __builtin_amdgcn_permlane32_swap(x, y, false, false);
        wreg[w] = r2.x;
        wreg[w + 2] = r2.y;
      }
      union { unsigned u[4]; s16x8 v; } pu;
      pu.u[0] = wreg[0]; pu.u[1] = wreg[1]; pu.u[2] = wreg[2]; pu.u[3] = wreg[3];
      pf[ks] = pu.v;
    }

    // PV (swapped): O^T[d][q]
    __builtin_amdgcn_s_setprio(1);
#pragma unroll
    for (int td = 0; td < 2; ++td)
#pragma unroll
      for (int ks = 0; ks < 4; ++ks) {
        int row = td * 32 + l31;
        s16x8 vf = *(const s16x8*)(Vs + row * 128 + ((ks * 32 + hi * 16) ^ ((row & 7) << 4)));
        oacc[td] = mfma32(vf, pf[ks], oacc[td]);
      }
    __builtin_amdgcn_s_setprio(0);

    asm volatile("s_waitcnt vmcnt(0)" ::: "memory");
    __syncthreads();
  }

  // epilogue: normalize, per-wave LDS transpose (4KB in buf0 region), coalesced store
  float inv = 1.0f / l;
  char* Ob = smem + wv * 4096;
#pragma unroll
  for (int td = 0; td < 2; ++td)
#pragma unroll
    for (int i = 0; i < 8; ++i) {
      int r = 2 * i;
      int d = td * 32 + (r & 3) + 8 * (r >> 2) + 4 * hi;
      unsigned pk = cvtpk_bf16(oacc[td][r] * inv, oacc[td][r + 1] * inv);
      *(unsigned*)(Ob + l31 * 128 + ((d * 2) ^ ((l31 & 7) << 4))) = pk;
    }
  // wave-local LDS (own 4KB region; last tile's buffers live at smem+16KB) — no barrier
#pragma unroll
  for (int p4 = 0; p4 < 4; ++p4) {
    int lq = p4 * 8 + (lane >> 3);
    int col = (lane & 7) * 16;
    s16x8 v0 = *(const s16x8*)(Ob + lq * 128 + (col ^ ((lq & 7) << 4)));
    int qg = blockIdx.x * 64 + wv * 32 + lq;
    *(s16x8*)((char*)&ob[((size_t)(b * NS + qg)) * NE + h * ND] + col) = v0;
  }
}

// ---------------- launch ----------------
extern "C" void kernel_launch(void* const* d_in, const int* in_sizes, int n_in,
                              void* d_out, int out_size, void* d_ws, size_t ws_size,
                              hipStream_t stream) {
  const float* queries = (const float*)d_in[0];
  const float* keys = (const float*)d_in[1];
  // d_in[2] (values) is unused by the reference
  const int* mask = (const int*)d_in[3];
  const float* Wq = (const float*)d_in[4];
  const float* bq = (const float*)d_in[5];
  const float* Wk = (const float*)d_in[6];
  const float* bk = (const float*)d_in[7];
  const float* Wv = (const float*)d_in[8];
  const float* bv = (const float*)d_in[9];
  const float* Wo = (const float*)d_in[10];
  const float* bo = (const float*)d_in[11];
  float* out = (float*)d_out;

  char* ws = (char*)d_ws;
  const size_t SZ_X = (size_t)NB * NS * NE * 2;  // 8 MiB
  const size_t SZ_W = (size_t)NE * NE * 2;       // 2 MiB
  unsigned short* qbf = (unsigned short*)(ws);
  unsigned short* kbf = (unsigned short*)(ws + SZ_X);
  unsigned short* wqb = (unsigned short*)(ws + 2 * SZ_X);
  unsigned short* wkb = (unsigned short*)(ws + 2 * SZ_X + SZ_W);
  unsigned short* wvb = (unsigned short*)(ws + 2 * SZ_X + 2 * SZ_W);
  unsigned short* wob = (unsigned short*)(ws + 2 * SZ_X + 3 * SZ_W);
  unsigned short* qp  = (unsigned short*)(ws + 2 * SZ_X + 4 * SZ_W);
  unsigned short* kp  = (unsigned short*)(ws + 3 * SZ_X + 4 * SZ_W);
  unsigned short* vtp = (unsigned short*)(ws + 4 * SZ_X + 4 * SZ_W);
  unsigned short* ao  = (unsigned short*)(ws + 5 * SZ_X + 4 * SZ_W);

  int nX4 = NB * NS * NE / 4, nW4 = NE * NE / 4;
  conv_x2<<<dim3(1024, 2), 256, 0, stream>>>(queries, keys, qbf, kbf, nX4);
  conv_w4<<<dim3(256, 4), 256, 0, stream>>>(Wq, Wk, Wv, Wo, wqb, wkb, wvb, wob, nW4);

  // Q projection: [4096,1024]x[1024,1024]^T -> qp (bf16)
  gemm_bt<0><<<dim3(8, 64), 256, 0, stream>>>(qbf, wqb, nullptr, bq, nullptr, qp, nullptr);
  // merged K+V projection: N=2048; K half -> kp (row-major), V half -> vtp (head-transposed)
  gemm_bt<3><<<dim3(16, 64), 256, 0, stream>>>(kbf, wkb, wvb, bk, bv, kp, vtp);

  dim3 ga(NS / 64, NB * NH);  // (32, 32)
  attn_fwd<<<ga, 128, 0, stream>>>(qp, kp, vtp, mask, ao);

  // output projection: f32 out
  gemm_bt<2><<<dim3(8, 64), 256, 0, stream>>>(ao, wob, nullptr, bo, nullptr, out, nullptr);
}

// Round 4
// 125.738 us; speedup vs baseline: 1.2991x; 1.2991x over previous
//
#include <hip/hip_runtime.h>
#include <hip/hip_bf16.h>
#include <stdint.h>

// Problem constants
#define NB 2
#define NS 2048
#define NE 1024
#define NH 16
#define ND 64

typedef __attribute__((ext_vector_type(4))) float f32x4;
typedef __attribute__((ext_vector_type(16))) float f32x16;
typedef __attribute__((ext_vector_type(8))) short s16x8;
typedef __attribute__((ext_vector_type(4))) unsigned short u16x4;
typedef __attribute__((ext_vector_type(2))) unsigned int uint2v;

__device__ __forceinline__ unsigned short f2bf(float f) {
  union { float f; unsigned int i; } u; u.f = f;
  unsigned int r = u.i + 0x7FFFu + ((u.i >> 16) & 1u);  // RNE
  return (unsigned short)(r >> 16);
}

__device__ __forceinline__ unsigned cvtpk_bf16(float lo, float hi) {
  unsigned r;
  asm("v_cvt_pk_bf16_f32 %0, %1, %2" : "=v"(r) : "v"(lo), "v"(hi));
  return r;
}

__device__ __forceinline__ void gload_lds16(const void* g, void* l) {
  __builtin_amdgcn_global_load_lds(
      (const __attribute__((address_space(1))) uint32_t*)g,
      (__attribute__((address_space(3))) uint32_t*)l, 16, 0, 0);
}

__device__ __forceinline__ f32x4 mfma16(s16x8 a, s16x8 b, f32x4 c) {
  return __builtin_amdgcn_mfma_f32_16x16x32_bf16(a, b, c, 0, 0, 0);
}
__device__ __forceinline__ f32x16 mfma32(s16x8 a, s16x8 b, f32x16 c) {
  return __builtin_amdgcn_mfma_f32_32x32x16_bf16(a, b, c, 0, 0, 0);
}

// ---------------- f32 -> bf16 converts (fused) ----------------
__global__ void conv_x2(const float* __restrict__ a, const float* __restrict__ b,
                        unsigned short* __restrict__ da, unsigned short* __restrict__ db,
                        int n4) {
  const float* s = blockIdx.y ? b : a;
  unsigned short* d = blockIdx.y ? db : da;
  int i = blockIdx.x * blockDim.x + threadIdx.x;
  int stride = gridDim.x * blockDim.x;
  for (; i < n4; i += stride) {
    float4 v = ((const float4*)s)[i];
    u16x4 o;
    o.x = f2bf(v.x); o.y = f2bf(v.y); o.z = f2bf(v.z); o.w = f2bf(v.w);
    ((u16x4*)d)[i] = o;
  }
}

__global__ void conv_w4(const float* __restrict__ s0, const float* __restrict__ s1,
                        const float* __restrict__ s2, const float* __restrict__ s3,
                        unsigned short* __restrict__ d0, unsigned short* __restrict__ d1,
                        unsigned short* __restrict__ d2, unsigned short* __restrict__ d3,
                        int n4) {
  const float* s; unsigned short* d;
  switch (blockIdx.y) {
    case 0: s = s0; d = d0; break;
    case 1: s = s1; d = d1; break;
    case 2: s = s2; d = d2; break;
    default: s = s3; d = d3; break;
  }
  int i = blockIdx.x * blockDim.x + threadIdx.x;
  int stride = gridDim.x * blockDim.x;
  for (; i < n4; i += stride) {
    float4 v = ((const float4*)s)[i];
    u16x4 o;
    o.x = f2bf(v.x); o.y = f2bf(v.y); o.z = f2bf(v.z); o.w = f2bf(v.w);
    ((u16x4*)d)[i] = o;
  }
}

// ---------------- GEMM: C = A[M,K] * W[N,K]^T + bias (M=4096, K=1024) ----------------
// Double-buffered LDS, counted vmcnt, raw barriers.
// EPI 0: bf16 out row-major [M,1024]
// EPI 2: f32  out row-major [M,1024]
// EPI 3: merged KV, N=2048: cols <1024 -> out0 bf16 row-major (W0,b0);
//        cols >=1024 -> out1 bf16 head-transposed [(b*NE+nv)*NS+s] (W1,b1)
template <int EPI>
__global__ __launch_bounds__(256, 2) void gemm_bt(
    const unsigned short* __restrict__ A,
    const unsigned short* __restrict__ W0, const unsigned short* __restrict__ W1,
    const float* __restrict__ b0, const float* __restrict__ b1,
    void* __restrict__ out0, void* __restrict__ out1) {
  constexpr int BM = 64;             // block rows; 2x2 waves of 32x64
  constexpr int K = 1024;
  __shared__ char smem[2 * (BM * 128 + 16384)];
  const int t = threadIdx.x;
  const int lane = t & 63;
  const int wv = t >> 6;
  const int wr = wv >> 1, wc = wv & 1;
  const int bm = blockIdx.y * BM, bn = blockIdx.x * 128;
  const int lr = lane & 15, lg = lane >> 4;

  const unsigned short* Wp = W0;
  const float* bp = b0;
  int nloc = bn;
  if constexpr (EPI == 3) {
    if (bn >= 1024) { Wp = W1; bp = b1; nloc = bn - 1024; }
  }

  f32x4 acc[2][4] = {};

  auto stage = [&](int buf, int k0) {
    char* As = smem + buf * (BM * 128 + 16384);
    char* Bs = As + BM * 128;
#pragma unroll
    for (int r = 0; r < BM / 32; ++r) {
      int lin = r * 256 + t;
      int row = lin >> 3;
      int scb = ((lin & 7) << 4) ^ ((row & 7) << 4);
      gload_lds16((const char*)(A + (size_t)(bm + row) * K + k0) + scb,
                  As + (size_t)(r * 256 + (t & ~63)) * 16);
    }
#pragma unroll
    for (int r = 0; r < 4; ++r) {
      int lin = r * 256 + t;
      int row = lin >> 3;
      int scb = ((lin & 7) << 4) ^ ((row & 7) << 4);
      gload_lds16((const char*)(Wp + (size_t)(nloc + row) * K + k0) + scb,
                  Bs + (size_t)(r * 256 + (t & ~63)) * 16);
    }
  };

  stage(0, 0);
  for (int t6 = 0; t6 < K / 64; ++t6) {
    const int cur = t6 & 1;
    if (t6 + 1 < K / 64) {
      stage(cur ^ 1, (t6 + 1) * 64);
      asm volatile("s_waitcnt vmcnt(6)" ::: "memory");  // 6 = next-tile loads in flight
    } else {
      asm volatile("s_waitcnt vmcnt(0)" ::: "memory");
    }
    asm volatile("s_barrier" ::: "memory");

    const char* As = smem + cur * (BM * 128 + 16384);
    const char* Bs = As + BM * 128;
    s16x8 af[2][2], bfr[4][2];
#pragma unroll
    for (int mf = 0; mf < 2; ++mf)
#pragma unroll
      for (int kk = 0; kk < 2; ++kk) {
        int row = wr * 32 + mf * 16 + lr;
        int cb = (lg << 4) + (kk << 6);
        af[mf][kk] = *(const s16x8*)(As + row * 128 + (cb ^ ((row & 7) << 4)));
      }
#pragma unroll
    for (int nf = 0; nf < 4; ++nf)
#pragma unroll
      for (int kk = 0; kk < 2; ++kk) {
        int row = wc * 64 + nf * 16 + lr;
        int cb = (lg << 4) + (kk << 6);
        bfr[nf][kk] = *(const s16x8*)(Bs + row * 128 + (cb ^ ((row & 7) << 4)));
      }
#pragma unroll
    for (int mf = 0; mf < 2; ++mf)
#pragma unroll
      for (int nf = 0; nf < 4; ++nf)
#pragma unroll
        for (int kk = 0; kk < 2; ++kk)
          acc[mf][nf] = mfma16(af[mf][kk], bfr[nf][kk], acc[mf][nf]);

    asm volatile("s_waitcnt lgkmcnt(0)" ::: "memory");  // reads landed before overwrite
    asm volatile("s_barrier" ::: "memory");
  }

  // epilogue: C/D layout col = lane&15, row = (lane>>4)*4 + reg
#pragma unroll
  for (int mf = 0; mf < 2; ++mf)
#pragma unroll
    for (int nf = 0; nf < 4; ++nf) {
      int m0 = bm + wr * 32 + mf * 16 + (lg << 2);
      int nc = wc * 64 + nf * 16 + lr;
      int n = bn + nc;
      float bv = bp[nloc + nc];
      if constexpr (EPI == 0) {
        unsigned short* C = (unsigned short*)out0;
#pragma unroll
        for (int r = 0; r < 4; ++r)
          C[(size_t)(m0 + r) * 1024 + n] = f2bf(acc[mf][nf][r] + bv);
      } else if constexpr (EPI == 2) {
        float* C = (float*)out0;
#pragma unroll
        for (int r = 0; r < 4; ++r)
          C[(size_t)(m0 + r) * 1024 + n] = acc[mf][nf][r] + bv;
      } else {  // EPI == 3
        if (n < 1024) {
          unsigned short* C = (unsigned short*)out0;
#pragma unroll
          for (int r = 0; r < 4; ++r)
            C[(size_t)(m0 + r) * 1024 + n] = f2bf(acc[mf][nf][r] + bv);
        } else {
          unsigned short* C = (unsigned short*)out1;
          int nv = n - 1024;
          int b = m0 >> 11, s = m0 & 2047;
          u16x4 o;
          o.x = f2bf(acc[mf][nf][0] + bv);
          o.y = f2bf(acc[mf][nf][1] + bv);
          o.z = f2bf(acc[mf][nf][2] + bv);
          o.w = f2bf(acc[mf][nf][3] + bv);
          *(u16x4*)&C[((size_t)b * NE + nv) * NS + s] = o;
        }
      }
    }
}

// ---------------- Flash attention (swapped-operand 32x32, 4 waves, QBLK=128) ----------------
// LDS tiles re-shaped to [32 rows][256B] so XOR-swizzle (row&15)<<4 spreads frag
// reads (32 lanes, 32 rows) across 16 slots -> 2-way (free). Staging keeps the
// LDS dest linear (global_load_lds) with the inverse permutation applied to the
// per-lane GLOBAL source address (rule #21).
__global__ __launch_bounds__(256, 2) void attn_fwd(
    const unsigned short* __restrict__ qb, const unsigned short* __restrict__ kb,
    const unsigned short* __restrict__ vt, const int* __restrict__ mask,
    unsigned short* __restrict__ ob) {
  __shared__ char smem[32768];  // 2 x (K 8KB + V 8KB)
  const int t = threadIdx.x, lane = t & 63, wv = t >> 6;
  const int l31 = lane & 31, hi = lane >> 5;
  const int sw = (l31 & 15) << 4;
  const int bh = blockIdx.y, b = bh >> 4, h = bh & 15;
  const int q = blockIdx.x * 128 + wv * 32 + l31;
  const float C = 0.18033688f;  // (1/sqrt(64)) * log2(e)

  // Q fragments (B-operand: col=q=lane&31, k = 16*ks + 8*hi + e)
  s16x8 qf[4];
#pragma unroll
  for (int ks = 0; ks < 4; ++ks)
    qf[ks] = *(const s16x8*)&qb[((size_t)(b * NS + q)) * NE + h * ND + ks * 16 + hi * 8];

  f32x16 oacc[2] = {};
  float m = -1e30f, l = 0.f;

  // K tile layout: key k, byte d2 of its 128B row -> LDS row=k&31,
  //   off=( (k>>5)*128 + d2 ) ^ ((row&15)<<4). V same with d as row index.
  auto stage = [&](int buf, int kt) {
    char* Ks = smem + buf * 16384;
    char* Vs = Ks + 8192;
#pragma unroll
    for (int r = 0; r < 2; ++r) {
      int L = (r * 256 + t) * 16;
      int row = L >> 8;
      int offp = (L & 255) ^ ((row & 15) << 4);
      int key = row + ((offp >> 7) << 5);
      int dby = offp & 127;
      gload_lds16((const char*)&kb[((size_t)(b * NS + kt + key)) * NE + h * ND] + dby,
                  Ks + (r * 256 + (t & ~63)) * 16);
    }
#pragma unroll
    for (int r = 0; r < 2; ++r) {
      int L = (r * 256 + t) * 16;
      int row = L >> 8;
      int offp = (L & 255) ^ ((row & 15) << 4);
      int d = row + ((offp >> 7) << 5);
      int kby = offp & 127;
      gload_lds16((const char*)&vt[((size_t)((b * NH + h) * ND + d)) * NS + kt] + kby,
                  Vs + (r * 256 + (t & ~63)) * 16);
    }
  };

  stage(0, 0);
  asm volatile("s_waitcnt vmcnt(0)" ::: "memory");
  __syncthreads();

  for (int kt = 0; kt < NS; kt += 64) {
    const int cur = (kt >> 6) & 1;
    if (kt + 64 < NS) stage(cur ^ 1, kt + 64);
    const char* Ks = smem + cur * 16384;
    const char* Vs = Ks + 8192;

    int mk = mask[b * NS + kt + lane];

    // QK^T (swapped): ST[key][q]; K frag row = l31, half bit = t2
    f32x16 st[2] = {};
    __builtin_amdgcn_s_setprio(1);
#pragma unroll
    for (int t2 = 0; t2 < 2; ++t2)
#pragma unroll
      for (int ks = 0; ks < 4; ++ks) {
        s16x8 kf = *(const s16x8*)(Ks + l31 * 256 +
                                   ((t2 * 128 + ks * 32 + hi * 16) ^ sw));
        st[t2] = mfma32(kf, qf[ks], st[t2]);
      }
    __builtin_amdgcn_s_setprio(0);

    // tile max: pairwise then max3-shaped tree, one cross-half exchange
    float tm[16];
#pragma unroll
    for (int r = 0; r < 16; ++r) tm[r] = fmaxf(st[0][r], st[1][r]);
    float a0 = fmaxf(fmaxf(tm[0], tm[1]), tm[2]);
    float a1 = fmaxf(fmaxf(tm[3], tm[4]), tm[5]);
    float a2 = fmaxf(fmaxf(tm[6], tm[7]), tm[8]);
    float a3 = fmaxf(fmaxf(tm[9], tm[10]), tm[11]);
    float a4 = fmaxf(fmaxf(tm[12], tm[13]), tm[14]);
    float b0 = fmaxf(fmaxf(a0, a1), a2);
    float b1 = fmaxf(fmaxf(a3, a4), tm[15]);
    float mxl = fmaxf(b0, b1);
    float mx = fmaxf(mxl, __shfl_xor(mxl, 32));

    // defer-max (T13)
    if (!__all(mx - m <= 44.0f)) {
      float mnew = fmaxf(m, mx);
      float corr = __builtin_amdgcn_exp2f((m - mnew) * C);
#pragma unroll
      for (int td = 0; td < 2; ++td)
#pragma unroll
        for (int r = 0; r < 16; ++r) oacc[td][r] *= corr;
      l *= corr;
      m = mnew;
    }
    const float mC = m * C;

    // exp in place
#pragma unroll
    for (int t2 = 0; t2 < 2; ++t2)
#pragma unroll
      for (int r = 0; r < 16; ++r)
        st[t2][r] = __builtin_amdgcn_exp2f(__builtin_fmaf(st[t2][r], C, -mC));

    // mask: zero p of masked keys (softmax invariant to inflated m)
    unsigned long long bal = __ballot(mk != 0);
    if (bal != ~0ull) {
#pragma unroll
      for (int t2 = 0; t2 < 2; ++t2)
#pragma unroll
        for (int r = 0; r < 16; ++r) {
          int key = t2 * 32 + (r & 3) + 8 * (r >> 2) + 4 * hi;
          if (!((bal >> key) & 1)) st[t2][r] = 0.f;
        }
    }

    // row sum
    float ps[16];
#pragma unroll
    for (int r = 0; r < 16; ++r) ps[r] = st[0][r] + st[1][r];
#pragma unroll
    for (int s = 8; s > 0; s >>= 1)
#pragma unroll
      for (int r = 0; r < s; ++r) ps[r] += ps[r + s];
    l += ps[0] + __shfl_xor(ps[0], 32);

    // pack P -> PV B-fragments (T12: cvt_pk + permlane32_swap)
    s16x8 pf[4];
#pragma unroll
    for (int ks = 0; ks < 4; ++ks) {
      const int t2 = ks >> 1, r0 = (ks & 1) * 8;
      unsigned wreg[4];
#pragma unroll
      for (int w = 0; w < 2; ++w) {
        unsigned x = cvtpk_bf16(st[t2][r0 + 2 * w], st[t2][r0 + 2 * w + 1]);
        unsigned y = cvtpk_bf16(st[t2][r0 + 4 + 2 * w], st[t2][r0 + 4 + 2 * w + 1]);
        uint2v r2 = __builtin_amdgcn_permlane32_swap(x, y, false, false);
        wreg[w] = r2.x;
        wreg[w + 2] = r2.y;
      }
      union { unsigned u[4]; s16x8 v; } pu;
      pu.u[0] = wreg[0]; pu.u[1] = wreg[1]; pu.u[2] = wreg[2]; pu.u[3] = wreg[3];
      pf[ks] = pu.v;
    }

    // PV (swapped): O^T[d][q]; V frag row = l31, half bit = td
    __builtin_amdgcn_s_setprio(1);
#pragma unroll
    for (int td = 0; td < 2; ++td)
#pragma unroll
      for (int ks = 0; ks < 4; ++ks) {
        s16x8 vf = *(const s16x8*)(Vs + l31 * 256 +
                                   ((td * 128 + ks * 32 + hi * 16) ^ sw));
        oacc[td] = mfma32(vf, pf[ks], oacc[td]);
      }
    __builtin_amdgcn_s_setprio(0);

    asm volatile("s_waitcnt vmcnt(0)" ::: "memory");
    __syncthreads();
  }

  // epilogue: normalize, per-wave LDS transpose (4KB), coalesced store
  float inv = 1.0f / l;
  char* Ob = smem + wv * 4096;
#pragma unroll
  for (int td = 0; td < 2; ++td)
#pragma unroll
    for (int i = 0; i < 8; ++i) {
      int r = 2 * i;
      int d = td * 32 + (r & 3) + 8 * (r >> 2) + 4 * hi;
      unsigned pk = cvtpk_bf16(oacc[td][r] * inv, oacc[td][r + 1] * inv);
      *(unsigned*)(Ob + l31 * 128 + ((d * 2) ^ ((l31 & 7) << 4))) = pk;
    }
  // wave-local LDS region; no barrier needed
#pragma unroll
  for (int p4 = 0; p4 < 4; ++p4) {
    int lq = p4 * 8 + (lane >> 3);
    int col = (lane & 7) * 16;
    s16x8 v0 = *(const s16x8*)(Ob + lq * 128 + (col ^ ((lq & 7) << 4)));
    int qg = blockIdx.x * 128 + wv * 32 + lq;
    *(s16x8*)((char*)&ob[((size_t)(b * NS + qg)) * NE + h * ND] + col) = v0;
  }
}

// ---------------- launch ----------------
extern "C" void kernel_launch(void* const* d_in, const int* in_sizes, int n_in,
                              void* d_out, int out_size, void* d_ws, size_t ws_size,
                              hipStream_t stream) {
  const float* queries = (const float*)d_in[0];
  const float* keys = (const float*)d_in[1];
  // d_in[2] (values) is unused by the reference
  const int* mask = (const int*)d_in[3];
  const float* Wq = (const float*)d_in[4];
  const float* bq = (const float*)d_in[5];
  const float* Wk = (const float*)d_in[6];
  const float* bk = (const float*)d_in[7];
  const float* Wv = (const float*)d_in[8];
  const float* bv = (const float*)d_in[9];
  const float* Wo = (const float*)d_in[10];
  const float* bo = (const float*)d_in[11];
  float* out = (float*)d_out;

  char* ws = (char*)d_ws;
  const size_t SZ_X = (size_t)NB * NS * NE * 2;  // 8 MiB
  const size_t SZ_W = (size_t)NE * NE * 2;       // 2 MiB
  unsigned short* qbf = (unsigned short*)(ws);
  unsigned short* kbf = (unsigned short*)(ws + SZ_X);
  unsigned short* wqb = (unsigned short*)(ws + 2 * SZ_X);
  unsigned short* wkb = (unsigned short*)(ws + 2 * SZ_X + SZ_W);
  unsigned short* wvb = (unsigned short*)(ws + 2 * SZ_X + 2 * SZ_W);
  unsigned short* wob = (unsigned short*)(ws + 2 * SZ_X + 3 * SZ_W);
  unsigned short* qp  = (unsigned short*)(ws + 2 * SZ_X + 4 * SZ_W);
  unsigned short* kp  = (unsigned short*)(ws + 3 * SZ_X + 4 * SZ_W);
  unsigned short* vtp = (unsigned short*)(ws + 4 * SZ_X + 4 * SZ_W);
  unsigned short* ao  = (unsigned short*)(ws + 5 * SZ_X + 4 * SZ_W);

  int nX4 = NB * NS * NE / 4, nW4 = NE * NE / 4;
  conv_x2<<<dim3(1024, 2), 256, 0, stream>>>(queries, keys, qbf, kbf, nX4);
  conv_w4<<<dim3(256, 4), 256, 0, stream>>>(Wq, Wk, Wv, Wo, wqb, wkb, wvb, wob, nW4);

  // Q projection: [4096,1024]x[1024,1024]^T -> qp (bf16)
  gemm_bt<0><<<dim3(8, 64), 256, 0, stream>>>(qbf, wqb, nullptr, bq, nullptr, qp, nullptr);
  // merged K+V projection: N=2048; K half -> kp (row-major), V half -> vtp (head-transposed)
  gemm_bt<3><<<dim3(16, 64), 256, 0, stream>>>(kbf, wkb, wvb, bk, bv, kp, vtp);

  dim3 ga(NS / 128, NB * NH);  // (16, 32)
  attn_fwd<<<ga, 256, 0, stream>>>(qp, kp, vtp, mask, ao);

  // output projection: f32 out
  gemm_bt<2><<<dim3(8, 64), 256, 0, stream>>>(ao, wob, nullptr, bo, nullptr, out, nullptr);
}

// Round 5
// 119.449 us; speedup vs baseline: 1.3675x; 1.0527x over previous
//
#include <hip/hip_runtime.h>
#include <hip/hip_bf16.h>
#include <stdint.h>

// Problem constants
#define NB 2
#define NS 2048
#define NE 1024
#define NH 16
#define ND 64
#define NT 32  // K-tiles (NS/64)

typedef __attribute__((ext_vector_type(4))) float f32x4;
typedef __attribute__((ext_vector_type(16))) float f32x16;
typedef __attribute__((ext_vector_type(8))) short s16x8;
typedef __attribute__((ext_vector_type(4))) unsigned short u16x4;
typedef __attribute__((ext_vector_type(2))) unsigned int uint2v;

__device__ __forceinline__ unsigned short f2bf(float f) {
  union { float f; unsigned int i; } u; u.f = f;
  unsigned int r = u.i + 0x7FFFu + ((u.i >> 16) & 1u);  // RNE
  return (unsigned short)(r >> 16);
}

__device__ __forceinline__ unsigned cvtpk_bf16(float lo, float hi) {
  unsigned r;
  asm("v_cvt_pk_bf16_f32 %0, %1, %2" : "=v"(r) : "v"(lo), "v"(hi));
  return r;
}

__device__ __forceinline__ void gload_lds16(const void* g, void* l) {
  __builtin_amdgcn_global_load_lds(
      (const __attribute__((address_space(1))) uint32_t*)g,
      (__attribute__((address_space(3))) uint32_t*)l, 16, 0, 0);
}

__device__ __forceinline__ f32x4 mfma16(s16x8 a, s16x8 b, f32x4 c) {
  return __builtin_amdgcn_mfma_f32_16x16x32_bf16(a, b, c, 0, 0, 0);
}
__device__ __forceinline__ f32x16 mfma32(s16x8 a, s16x8 b, f32x16 c) {
  return __builtin_amdgcn_mfma_f32_32x32x16_bf16(a, b, c, 0, 0, 0);
}

// ---------------- f32 -> bf16 converts (fused) ----------------
__global__ void conv_x2(const float* __restrict__ a, const float* __restrict__ b,
                        unsigned short* __restrict__ da, unsigned short* __restrict__ db,
                        int n4) {
  const float* s = blockIdx.y ? b : a;
  unsigned short* d = blockIdx.y ? db : da;
  int i = blockIdx.x * blockDim.x + threadIdx.x;
  int stride = gridDim.x * blockDim.x;
  for (; i < n4; i += stride) {
    float4 v = ((const float4*)s)[i];
    u16x4 o;
    o.x = f2bf(v.x); o.y = f2bf(v.y); o.z = f2bf(v.z); o.w = f2bf(v.w);
    ((u16x4*)d)[i] = o;
  }
}

__global__ void conv_w4(const float* __restrict__ s0, const float* __restrict__ s1,
                        const float* __restrict__ s2, const float* __restrict__ s3,
                        unsigned short* __restrict__ d0, unsigned short* __restrict__ d1,
                        unsigned short* __restrict__ d2, unsigned short* __restrict__ d3,
                        int n4) {
  const float* s; unsigned short* d;
  switch (blockIdx.y) {
    case 0: s = s0; d = d0; break;
    case 1: s = s1; d = d1; break;
    case 2: s = s2; d = d2; break;
    default: s = s3; d = d3; break;
  }
  int i = blockIdx.x * blockDim.x + threadIdx.x;
  int stride = gridDim.x * blockDim.x;
  for (; i < n4; i += stride) {
    float4 v = ((const float4*)s)[i];
    u16x4 o;
    o.x = f2bf(v.x); o.y = f2bf(v.y); o.z = f2bf(v.z); o.w = f2bf(v.w);
    ((u16x4*)d)[i] = o;
  }
}

// ---------------- mask -> per-tile uint64 bitmask ----------------
__global__ void mask_pack(const int* __restrict__ mask, unsigned long long* __restrict__ bm) {
  int w = blockIdx.x;            // word = 64-key tile, NB*NS/64 = 64 words
  int lane = threadIdx.x;        // 64 threads
  int mk = mask[w * 64 + lane];
  unsigned long long bal = __ballot(mk != 0);
  if (lane == 0) bm[w] = bal;
}

// ---------------- fused QKV projection GEMM ----------------
// grid (24, 64): x<8 -> Q (A=Aq,W=Wq) row-major out; x<16 -> K row-major;
// else V head-transposed out[(b*NE+n)*NS+s]. BM=64, BN=128, BK=64, dbuf.
__global__ __launch_bounds__(256, 3) void gemm_qkv(
    const unsigned short* __restrict__ Aq, const unsigned short* __restrict__ Akv,
    const unsigned short* __restrict__ Wqp, const unsigned short* __restrict__ Wkp,
    const unsigned short* __restrict__ Wvp,
    const float* __restrict__ bqp, const float* __restrict__ bkp, const float* __restrict__ bvp,
    unsigned short* __restrict__ outq, unsigned short* __restrict__ outk,
    unsigned short* __restrict__ outvt) {
  constexpr int BM = 64, K = 1024;
  __shared__ char smem[2 * (BM * 128 + 16384)];
  const int t = threadIdx.x;
  const int lane = t & 63;
  const int wv = t >> 6;
  const int wr = wv >> 1, wc = wv & 1;
  const int x = blockIdx.x;
  const int bm = blockIdx.y * BM;
  const int lr = lane & 15, lg = lane >> 4;

  const unsigned short* A; const unsigned short* Wp; const float* bp;
  unsigned short* outp; int nloc, mode;
  if (x < 8)       { A = Aq;  Wp = Wqp; bp = bqp; outp = outq;  nloc = x * 128;        mode = 0; }
  else if (x < 16) { A = Akv; Wp = Wkp; bp = bkp; outp = outk;  nloc = (x - 8) * 128;  mode = 0; }
  else             { A = Akv; Wp = Wvp; bp = bvp; outp = outvt; nloc = (x - 16) * 128; mode = 1; }

  f32x4 acc[2][4] = {};

  auto stage = [&](int buf, int k0) {
    char* As = smem + buf * (BM * 128 + 16384);
    char* Bs = As + BM * 128;
#pragma unroll
    for (int r = 0; r < 2; ++r) {
      int lin = r * 256 + t;
      int row = lin >> 3;
      int scb = ((lin & 7) << 4) ^ ((row & 7) << 4);
      gload_lds16((const char*)(A + (size_t)(bm + row) * K + k0) + scb,
                  As + (size_t)(r * 256 + (t & ~63)) * 16);
    }
#pragma unroll
    for (int r = 0; r < 4; ++r) {
      int lin = r * 256 + t;
      int row = lin >> 3;
      int scb = ((lin & 7) << 4) ^ ((row & 7) << 4);
      gload_lds16((const char*)(Wp + (size_t)(nloc + row) * K + k0) + scb,
                  Bs + (size_t)(r * 256 + (t & ~63)) * 16);
    }
  };

  stage(0, 0);
  for (int t6 = 0; t6 < K / 64; ++t6) {
    const int cur = t6 & 1;
    if (t6 + 1 < K / 64) {
      stage(cur ^ 1, (t6 + 1) * 64);
      asm volatile("s_waitcnt vmcnt(6)" ::: "memory");
    } else {
      asm volatile("s_waitcnt vmcnt(0)" ::: "memory");
    }
    asm volatile("s_barrier" ::: "memory");

    const char* As = smem + cur * (BM * 128 + 16384);
    const char* Bs = As + BM * 128;
    s16x8 af[2][2], bfr[4][2];
#pragma unroll
    for (int mf = 0; mf < 2; ++mf)
#pragma unroll
      for (int kk = 0; kk < 2; ++kk) {
        int row = wr * 32 + mf * 16 + lr;
        int cb = (lg << 4) + (kk << 6);
        af[mf][kk] = *(const s16x8*)(As + row * 128 + (cb ^ ((row & 7) << 4)));
      }
#pragma unroll
    for (int nf = 0; nf < 4; ++nf)
#pragma unroll
      for (int kk = 0; kk < 2; ++kk) {
        int row = wc * 64 + nf * 16 + lr;
        int cb = (lg << 4) + (kk << 6);
        bfr[nf][kk] = *(const s16x8*)(Bs + row * 128 + (cb ^ ((row & 7) << 4)));
      }
#pragma unroll
    for (int mf = 0; mf < 2; ++mf)
#pragma unroll
      for (int nf = 0; nf < 4; ++nf)
#pragma unroll
        for (int kk = 0; kk < 2; ++kk)
          acc[mf][nf] = mfma16(af[mf][kk], bfr[nf][kk], acc[mf][nf]);

    asm volatile("s_waitcnt lgkmcnt(0)" ::: "memory");
    asm volatile("s_barrier" ::: "memory");
  }

#pragma unroll
  for (int mf = 0; mf < 2; ++mf)
#pragma unroll
    for (int nf = 0; nf < 4; ++nf) {
      int m0 = bm + wr * 32 + mf * 16 + (lg << 2);
      int nc = wc * 64 + nf * 16 + lr;
      float bv = bp[nloc + nc];
      if (mode == 0) {
#pragma unroll
        for (int r = 0; r < 4; ++r)
          outp[(size_t)(m0 + r) * 1024 + nloc + nc] = f2bf(acc[mf][nf][r] + bv);
      } else {
        int b = m0 >> 11, s = m0 & 2047;
        u16x4 o;
        o.x = f2bf(acc[mf][nf][0] + bv);
        o.y = f2bf(acc[mf][nf][1] + bv);
        o.z = f2bf(acc[mf][nf][2] + bv);
        o.w = f2bf(acc[mf][nf][3] + bv);
        *(u16x4*)&outp[((size_t)b * NE + nloc + nc) * NS + s] = o;
      }
    }
}

// ---------------- O-projection GEMM (f32 out) ----------------
__global__ __launch_bounds__(256, 3) void gemm_o(
    const unsigned short* __restrict__ A, const unsigned short* __restrict__ W,
    const float* __restrict__ bias, float* __restrict__ out) {
  constexpr int BM = 64, K = 1024;
  __shared__ char smem[2 * (BM * 128 + 16384)];
  const int t = threadIdx.x;
  const int lane = t & 63;
  const int wv = t >> 6;
  const int wr = wv >> 1, wc = wv & 1;
  const int bm = blockIdx.y * BM, bn = blockIdx.x * 128;
  const int lr = lane & 15, lg = lane >> 4;

  f32x4 acc[2][4] = {};

  auto stage = [&](int buf, int k0) {
    char* As = smem + buf * (BM * 128 + 16384);
    char* Bs = As + BM * 128;
#pragma unroll
    for (int r = 0; r < 2; ++r) {
      int lin = r * 256 + t;
      int row = lin >> 3;
      int scb = ((lin & 7) << 4) ^ ((row & 7) << 4);
      gload_lds16((const char*)(A + (size_t)(bm + row) * K + k0) + scb,
                  As + (size_t)(r * 256 + (t & ~63)) * 16);
    }
#pragma unroll
    for (int r = 0; r < 4; ++r) {
      int lin = r * 256 + t;
      int row = lin >> 3;
      int scb = ((lin & 7) << 4) ^ ((row & 7) << 4);
      gload_lds16((const char*)(W + (size_t)(bn + row) * K + k0) + scb,
                  Bs + (size_t)(r * 256 + (t & ~63)) * 16);
    }
  };

  stage(0, 0);
  for (int t6 = 0; t6 < K / 64; ++t6) {
    const int cur = t6 & 1;
    if (t6 + 1 < K / 64) {
      stage(cur ^ 1, (t6 + 1) * 64);
      asm volatile("s_waitcnt vmcnt(6)" ::: "memory");
    } else {
      asm volatile("s_waitcnt vmcnt(0)" ::: "memory");
    }
    asm volatile("s_barrier" ::: "memory");

    const char* As = smem + cur * (BM * 128 + 16384);
    const char* Bs = As + BM * 128;
    s16x8 af[2][2], bfr[4][2];
#pragma unroll
    for (int mf = 0; mf < 2; ++mf)
#pragma unroll
      for (int kk = 0; kk < 2; ++kk) {
        int row = wr * 32 + mf * 16 + lr;
        int cb = (lg << 4) + (kk << 6);
        af[mf][kk] = *(const s16x8*)(As + row * 128 + (cb ^ ((row & 7) << 4)));
      }
#pragma unroll
    for (int nf = 0; nf < 4; ++nf)
#pragma unroll
      for (int kk = 0; kk < 2; ++kk) {
        int row = wc * 64 + nf * 16 + lr;
        int cb = (lg << 4) + (kk << 6);
        bfr[nf][kk] = *(const s16x8*)(Bs + row * 128 + (cb ^ ((row & 7) << 4)));
      }
#pragma unroll
    for (int mf = 0; mf < 2; ++mf)
#pragma unroll
      for (int nf = 0; nf < 4; ++nf)
#pragma unroll
        for (int kk = 0; kk < 2; ++kk)
          acc[mf][nf] = mfma16(af[mf][kk], bfr[nf][kk], acc[mf][nf]);

    asm volatile("s_waitcnt lgkmcnt(0)" ::: "memory");
    asm volatile("s_barrier" ::: "memory");
  }

#pragma unroll
  for (int mf = 0; mf < 2; ++mf)
#pragma unroll
    for (int nf = 0; nf < 4; ++nf) {
      int m0 = bm + wr * 32 + mf * 16 + (lg << 2);
      int n = bn + wc * 64 + nf * 16 + lr;
      float bv = bias[n];
#pragma unroll
      for (int r = 0; r < 4; ++r)
        out[(size_t)(m0 + r) * 1024 + n] = acc[mf][nf][r] + bv;
    }
}

// ---------------- Flash attention: depth-2 pipeline, 4 LDS buffers ----------------
// grid (S/128, B*H), 256 threads = 4 waves; wave owns 32 q-rows.
// Swapped-operand 32x32 MFMA; in-register softmax; no VMEM in K-loop except staging.
__global__ __launch_bounds__(256, 2) void attn_fwd(
    const unsigned short* __restrict__ qb, const unsigned short* __restrict__ kb,
    const unsigned short* __restrict__ vt, const unsigned long long* __restrict__ bmw,
    unsigned short* __restrict__ ob) {
  __shared__ char smem[65536];  // 4 bufs x (K 8KB | V 8KB)
  const int t = threadIdx.x, lane = t & 63, wv = t >> 6;
  const int l31 = lane & 31, hi = lane >> 5;
  const int sw = (l31 & 15) << 4;
  const int bh = blockIdx.y, b = bh >> 4, h = bh & 15;
  const int q = blockIdx.x * 128 + wv * 32 + l31;
  const float C = 0.18033688f;  // (1/sqrt(64)) * log2(e)

  // Q fragments (B-operand: col=q=lane&31, k = 16*ks + 8*hi + e)
  s16x8 qf[4];
#pragma unroll
  for (int ks = 0; ks < 4; ++ks)
    qf[ks] = *(const s16x8*)&qb[((size_t)(b * NS + q)) * NE + h * ND + ks * 16 + hi * 8];

  // mask bitmask words: lane i holds word for tile (i&31)
  unsigned long long mword = bmw[(size_t)b * 32 + l31];
  unsigned mlo = (unsigned)mword, mhi = (unsigned)(mword >> 32);

  // staging source addresses (per-thread, hoisted); inverse-swizzled global src
  const char* kSrc[2]; const char* vSrc[2]; int ldsK[2], ldsV[2];
#pragma unroll
  for (int r = 0; r < 2; ++r) {
    int L = (r * 256 + t) * 16;
    int row = L >> 8;
    int offp = (L & 255) ^ ((row & 15) << 4);
    int rr = row + ((offp >> 7) << 5);
    int byo = offp & 127;
    kSrc[r] = (const char*)&kb[((size_t)(b * NS) + rr) * NE + h * ND] + byo;
    vSrc[r] = (const char*)&vt[((size_t)((b * NH + h) * ND) + rr) * NS] + byo;
    ldsK[r] = (r * 256 + (t & ~63)) * 16;
    ldsV[r] = 8192 + ldsK[r];
  }

  // frag LDS offsets: off[j] for j=0..7 covers (t2*128 + ks*32) ^ sw; K,V share
  int off16[8];
#pragma unroll
  for (int j = 0; j < 8; ++j)
    off16[j] = l31 * 256 + ((j * 32 + hi * 16) ^ sw);

  auto stage = [&](int buf, int kt) {
    char* base = smem + buf * 16384;
#pragma unroll
    for (int r = 0; r < 2; ++r)
      gload_lds16(kSrc[r] + (size_t)kt * (NE * 2), base + ldsK[r]);
#pragma unroll
    for (int r = 0; r < 2; ++r)
      gload_lds16(vSrc[r] + (size_t)kt * 2, base + ldsV[r]);
  };

  f32x16 oacc[2] = {};
  float m = -1e30f, l = 0.f;

  stage(0, 0);
  stage(1, 64);
  asm volatile("s_waitcnt vmcnt(0)" ::: "memory");
  __syncthreads();

  auto body = [&](int tt, int buf) {
    if (tt + 2 < NT) {
      stage((buf + 2) & 3, (tt + 2) * 64);
      asm volatile("s_waitcnt vmcnt(8)" ::: "memory");
    } else if (tt + 1 < NT) {
      asm volatile("s_waitcnt vmcnt(4)" ::: "memory");
    } else {
      asm volatile("s_waitcnt vmcnt(0)" ::: "memory");
    }
    __builtin_amdgcn_s_barrier();

    const char* Ks = smem + buf * 16384;
    const char* Vs = Ks + 8192;

    // QK^T (swapped): ST[key][q]
    f32x16 st[2] = {};
    __builtin_amdgcn_s_setprio(1);
#pragma unroll
    for (int t2 = 0; t2 < 2; ++t2)
#pragma unroll
      for (int ks = 0; ks < 4; ++ks) {
        s16x8 kf = *(const s16x8*)(Ks + off16[t2 * 4 + ks]);
        st[t2] = mfma32(kf, qf[ks], st[t2]);
      }
    __builtin_amdgcn_s_setprio(0);

    // tile max
    float tm[16];
#pragma unroll
    for (int r = 0; r < 16; ++r) tm[r] = fmaxf(st[0][r], st[1][r]);
    float a0 = fmaxf(fmaxf(tm[0], tm[1]), tm[2]);
    float a1 = fmaxf(fmaxf(tm[3], tm[4]), tm[5]);
    float a2 = fmaxf(fmaxf(tm[6], tm[7]), tm[8]);
    float a3 = fmaxf(fmaxf(tm[9], tm[10]), tm[11]);
    float a4 = fmaxf(fmaxf(tm[12], tm[13]), tm[14]);
    float b0 = fmaxf(fmaxf(a0, a1), a2);
    float b1 = fmaxf(fmaxf(a3, a4), tm[15]);
    float mxl = fmaxf(b0, b1);
    float mx = fmaxf(mxl, __shfl_xor(mxl, 32));

    // defer-max (T13)
    if (!__all(mx - m <= 44.0f)) {
      float mnew = fmaxf(m, mx);
      float corr = __builtin_amdgcn_exp2f((m - mnew) * C);
#pragma unroll
      for (int td = 0; td < 2; ++td)
#pragma unroll
        for (int r = 0; r < 16; ++r) oacc[td][r] *= corr;
      l *= corr;
      m = mnew;
    }
    const float mC = m * C;

    // exp in place
#pragma unroll
    for (int t2 = 0; t2 < 2; ++t2)
#pragma unroll
      for (int r = 0; r < 16; ++r)
        st[t2][r] = __builtin_amdgcn_exp2f(__builtin_fmaf(st[t2][r], C, -mC));

    // mask via prepacked bitmask (scalar fast path when all-ones)
    unsigned lo = (unsigned)__builtin_amdgcn_readlane((int)mlo, tt);
    unsigned hh = (unsigned)__builtin_amdgcn_readlane((int)mhi, tt);
    unsigned long long bal = ((unsigned long long)hh << 32) | lo;
    if (bal != ~0ull) {
#pragma unroll
      for (int t2 = 0; t2 < 2; ++t2)
#pragma unroll
        for (int r = 0; r < 16; ++r) {
          int key = t2 * 32 + (r & 3) + 8 * (r >> 2) + 4 * hi;
          if (!((bal >> key) & 1)) st[t2][r] = 0.f;
        }
    }

    // row sum
    float ps[16];
#pragma unroll
    for (int r = 0; r < 16; ++r) ps[r] = st[0][r] + st[1][r];
#pragma unroll
    for (int s = 8; s > 0; s >>= 1)
#pragma unroll
      for (int r = 0; r < s; ++r) ps[r] += ps[r + s];
    l += ps[0] + __shfl_xor(ps[0], 32);

    // pack P -> PV B-fragments (T12: cvt_pk + permlane32_swap)
    s16x8 pf[4];
#pragma unroll
    for (int ks = 0; ks < 4; ++ks) {
      const int t2 = ks >> 1, r0 = (ks & 1) * 8;
      unsigned wreg[4];
#pragma unroll
      for (int w = 0; w < 2; ++w) {
        unsigned x = cvtpk_bf16(st[t2][r0 + 2 * w], st[t2][r0 + 2 * w + 1]);
        unsigned y = cvtpk_bf16(st[t2][r0 + 4 + 2 * w], st[t2][r0 + 4 + 2 * w + 1]);
        uint2v r2 = __builtin_amdgcn_permlane32_swap(x, y, false, false);
        wreg[w] = r2.x;
        wreg[w + 2] = r2.y;
      }
      union { unsigned u[4]; s16x8 v; } pu;
      pu.u[0] = wreg[0]; pu.u[1] = wreg[1]; pu.u[2] = wreg[2]; pu.u[3] = wreg[3];
      pf[ks] = pu.v;
    }

    // PV (swapped): O^T[d][q]
    __builtin_amdgcn_s_setprio(1);
#pragma unroll
    for (int td = 0; td < 2; ++td)
#pragma unroll
      for (int ks = 0; ks < 4; ++ks) {
        s16x8 vf = *(const s16x8*)(Vs + off16[td * 4 + ks]);
        oacc[td] = mfma32(vf, pf[ks], oacc[td]);
      }
    __builtin_amdgcn_s_setprio(0);
  };

  for (int tt = 0; tt < NT; tt += 4) {
    body(tt + 0, 0);
    body(tt + 1, 1);
    body(tt + 2, 2);
    body(tt + 3, 3);
  }

  // epilogue: normalize, per-wave LDS transpose (4KB), coalesced store
  float inv = 1.0f / l;
  char* Ob = smem + wv * 4096;
#pragma unroll
  for (int td = 0; td < 2; ++td)
#pragma unroll
    for (int i = 0; i < 8; ++i) {
      int r = 2 * i;
      int d = td * 32 + (r & 3) + 8 * (r >> 2) + 4 * hi;
      unsigned pk = cvtpk_bf16(oacc[td][r] * inv, oacc[td][r + 1] * inv);
      *(unsigned*)(Ob + l31 * 128 + ((d * 2) ^ ((l31 & 7) << 4))) = pk;
    }
  // wave-local region; no barrier needed
#pragma unroll
  for (int p4 = 0; p4 < 4; ++p4) {
    int lq = p4 * 8 + (lane >> 3);
    int col = (lane & 7) * 16;
    s16x8 v0 = *(const s16x8*)(Ob + lq * 128 + (col ^ ((lq & 7) << 4)));
    int qg = blockIdx.x * 128 + wv * 32 + lq;
    *(s16x8*)((char*)&ob[((size_t)(b * NS + qg)) * NE + h * ND] + col) = v0;
  }
}

// ---------------- launch ----------------
extern "C" void kernel_launch(void* const* d_in, const int* in_sizes, int n_in,
                              void* d_out, int out_size, void* d_ws, size_t ws_size,
                              hipStream_t stream) {
  const float* queries = (const float*)d_in[0];
  const float* keys = (const float*)d_in[1];
  // d_in[2] (values) is unused by the reference
  const int* mask = (const int*)d_in[3];
  const float* Wq = (const float*)d_in[4];
  const float* bq = (const float*)d_in[5];
  const float* Wk = (const float*)d_in[6];
  const float* bk = (const float*)d_in[7];
  const float* Wv = (const float*)d_in[8];
  const float* bv = (const float*)d_in[9];
  const float* Wo = (const float*)d_in[10];
  const float* bo = (const float*)d_in[11];
  float* out = (float*)d_out;

  char* ws = (char*)d_ws;
  const size_t SZ_X = (size_t)NB * NS * NE * 2;  // 8 MiB
  const size_t SZ_W = (size_t)NE * NE * 2;       // 2 MiB
  unsigned short* qbf = (unsigned short*)(ws);
  unsigned short* kbf = (unsigned short*)(ws + SZ_X);
  unsigned short* wqb = (unsigned short*)(ws + 2 * SZ_X);
  unsigned short* wkb = (unsigned short*)(ws + 2 * SZ_X + SZ_W);
  unsigned short* wvb = (unsigned short*)(ws + 2 * SZ_X + 2 * SZ_W);
  unsigned short* wob = (unsigned short*)(ws + 2 * SZ_X + 3 * SZ_W);
  unsigned short* qp  = (unsigned short*)(ws + 2 * SZ_X + 4 * SZ_W);
  unsigned short* kp  = (unsigned short*)(ws + 3 * SZ_X + 4 * SZ_W);
  unsigned short* vtp = (unsigned short*)(ws + 4 * SZ_X + 4 * SZ_W);
  unsigned short* ao  = (unsigned short*)(ws + 5 * SZ_X + 4 * SZ_W);
  unsigned long long* bmp = (unsigned long long*)(ws + 6 * SZ_X + 4 * SZ_W);

  int nX4 = NB * NS * NE / 4, nW4 = NE * NE / 4;
  conv_x2<<<dim3(1024, 2), 256, 0, stream>>>(queries, keys, qbf, kbf, nX4);
  conv_w4<<<dim3(256, 4), 256, 0, stream>>>(Wq, Wk, Wv, Wo, wqb, wkb, wvb, wob, nW4);
  mask_pack<<<NB * NS / 64, 64, 0, stream>>>(mask, bmp);

  // fused Q + K + V projections
  gemm_qkv<<<dim3(24, 64), 256, 0, stream>>>(qbf, kbf, wqb, wkb, wvb,
                                             bq, bk, bv, qp, kp, vtp);

  dim3 ga(NS / 128, NB * NH);  // (16, 32)
  attn_fwd<<<ga, 256, 0, stream>>>(qp, kp, vtp, bmp, ao);

  // output projection: f32 out
  gemm_o<<<dim3(8, 64), 256, 0, stream>>>(ao, wob, bo, out);
}